// Round 6
// baseline (439.373 us; speedup 1.0000x reference)
//
#include <hip/hip_runtime.h>
#include <math.h>

#define D_MODEL 256
#define N_EXP   16
#define N_VIEWS 3
#define N_TOK   8192
#define TOPK    4
#define HDIM    1024
#define CH      64
#define NCH     16
#define ROWS    64             // rows per ffn tile
#define NGROUP  48
#define NT_STRIPE 2048         // 8 XCD lanes x 256 slots
#define NT_SPILL  512
#define NT_TOTAL  (NT_STRIPE + NT_SPILL)   // worst case 768 tiles/XCD fits stripe+spill
#define REC_ELTS 32768         // chunk record: W1 half (16384) + W2 half (16384) shorts

typedef short s16x8 __attribute__((ext_vector_type(8)));
typedef float f32x4 __attribute__((ext_vector_type(4)));
typedef float f32x16 __attribute__((ext_vector_type(16)));

__device__ __forceinline__ unsigned short f2bf(float x) {
    union { float f; unsigned u; } a; a.f = x;
    unsigned r = a.u + 0x7FFFu + ((a.u >> 16) & 1u);   // RNE
    return (unsigned short)(r >> 16);
}

// async global -> LDS, 16 B per lane; LDS dst is wave-uniform base + lane*16
__device__ __forceinline__ void dma16(const unsigned short* gp, unsigned short* lp) {
    __builtin_amdgcn_global_load_lds(
        (const __attribute__((address_space(1))) unsigned int*)gp,
        (__attribute__((address_space(3))) unsigned int*)lp, 16, 0, 0);
}

// stage one 32 KB half-record: 8 waves x 4 instr x 1 KB
__device__ __forceinline__ void dma_half(const unsigned short* gsrc, unsigned short* ldst,
                                         int wave, int lane) {
    #pragma unroll
    for (int i = 0; i < 4; i++) {
        int blk = wave * 4 + i;                       // 0..31, 1 KB blocks
        dma16(gsrc + ((size_t)blk * 64 + lane) * 8, ldst + blk * 512);
    }
}

// ------------------------------------------------------------------
// 32x32x16 fragment records.
// W1 half: frag idx=(kt*2+nh)*64+l : elem = W1[e][kt*16+(l>>5)*8+j][c*64+nh*32+(l&31)]
// W2 half: frag idx=(kt2*8+nt)*64+l: elem = W2[e][c*64+kt2*16+(l>>5)*8+j][nt*32+(l&31)]
// ------------------------------------------------------------------
__global__ __launch_bounds__(256) void wfrag_kernel(const float* __restrict__ W1,
                                                    const float* __restrict__ W2,
                                                    unsigned short* __restrict__ Wf) {
    int c = blockIdx.x, e = blockIdx.y;
    unsigned short* dst = Wf + (size_t)(e * NCH + c) * REC_ELTS;
    if (blockIdx.z == 0) {
        const float* src = W1 + (size_t)e * 256 * 1024;
        #pragma unroll
        for (int i = 0; i < 8; i++) {
            int idx = threadIdx.x + i * 256;
            int lane = idx & 63, nh = (idx >> 6) & 1, kt = idx >> 7;
            int ncol = c * 64 + nh * 32 + (lane & 31);
            int kbase = kt * 16 + (lane >> 5) * 8;
            s16x8 o;
            #pragma unroll
            for (int j = 0; j < 8; j++) o[j] = (short)f2bf(src[(size_t)(kbase + j) * 1024 + ncol]);
            *(s16x8*)(dst + (size_t)idx * 8) = o;
        }
    } else {
        const float* src = W2 + (size_t)e * 1024 * 256;
        dst += 16384;
        #pragma unroll
        for (int i = 0; i < 8; i++) {
            int idx = threadIdx.x + i * 256;
            int lane = idx & 63, nt = (idx >> 6) & 7, kt2 = idx >> 9;
            int n = nt * 32 + (lane & 31);
            int kbase = c * 64 + kt2 * 16 + (lane >> 5) * 8;
            s16x8 o;
            #pragma unroll
            for (int j = 0; j < 8; j++) o[j] = (short)f2bf(src[(size_t)(kbase + j) * 256 + n]);
            *(s16x8*)(dst + (size_t)idx * 8) = o;
        }
    }
}

// ------------------------------------------------------------------
// routing (fused: cw/knorm build + bf16 X copy + logits + top4 + softmax)
// ------------------------------------------------------------------
__global__ __launch_bounds__(256) void route_kernel(
    const float* __restrict__ v0, const float* __restrict__ v1, const float* __restrict__ v2,
    const float* __restrict__ rw, const float* __restrict__ keys,
    unsigned short* __restrict__ Xbf,
    int* __restrict__ gidx, float* __restrict__ ggate, int* __restrict__ counts)
{
    __shared__ __align__(16) float cwS[N_EXP * D_MODEL];
    __shared__ float knS[N_EXP];
    __shared__ int lcnt[N_EXP];
    int view = blockIdx.y;
    const float* src = view == 0 ? v0 : (view == 1 ? v1 : v2);
    for (int i = threadIdx.x; i < N_EXP * D_MODEL; i += 256)
        cwS[i] = rw[view * N_EXP * D_MODEL + i] + 2.0f * keys[i];
    if (threadIdx.x < N_EXP) {
        const float4* kp = (const float4*)(keys + threadIdx.x * D_MODEL);
        float s = 0.f;
        for (int d = 0; d < 64; d++) { float4 k = kp[d]; s += k.x*k.x + k.y*k.y + k.z*k.z + k.w*k.w; }
        knS[threadIdx.x] = s; lcnt[threadIdx.x] = 0;
    }
    __syncthreads();

    int wave = threadIdx.x >> 6, lane = threadIdx.x & 63;
    for (int t = 0; t < 16; t++) {
        int token = blockIdx.x * 64 + wave * 16 + t;
        float4 v = ((const float4*)(src + (size_t)token * D_MODEL))[lane];
        ushort4 xo; xo.x = f2bf(v.x); xo.y = f2bf(v.y); xo.z = f2bf(v.z); xo.w = f2bf(v.w);
        ((ushort4*)(Xbf + ((size_t)view * N_TOK + token) * D_MODEL))[lane] = xo;
        float lg[N_EXP];
        #pragma unroll
        for (int e = 0; e < N_EXP; e++) {
            float4 w = *(const float4*)&cwS[e * D_MODEL + lane * 4];
            float p = v.x * w.x + v.y * w.y + v.z * w.z + v.w * w.w;
            #pragma unroll
            for (int s = 32; s > 0; s >>= 1) p += __shfl_xor(p, s, 64);
            lg[e] = p - knS[e];
        }
        int idxs[TOPK]; float vals[TOPK];
        #pragma unroll
        for (int k = 0; k < TOPK; k++) {
            float best = -1e30f; int bi = 0;
            #pragma unroll
            for (int e = 0; e < N_EXP; e++)
                if (lg[e] > best) { best = lg[e]; bi = e; }
            idxs[k] = bi; vals[k] = best;
            #pragma unroll
            for (int e = 0; e < N_EXP; e++)
                lg[e] = (e == bi) ? -1e30f : lg[e];
        }
        float m = vals[0], s = 0.f, ex[TOPK];
        #pragma unroll
        for (int k = 0; k < TOPK; k++) { ex[k] = __expf(vals[k] - m); s += ex[k]; }
        float inv = 1.0f / s;
        if (lane == 0) {
            size_t t4 = ((size_t)view * N_TOK + token) * TOPK;
            int4 gi; gi.x = idxs[0]; gi.y = idxs[1]; gi.z = idxs[2]; gi.w = idxs[3];
            *(int4*)&gidx[t4] = gi;
            float4 gv; gv.x = ex[0]*inv; gv.y = ex[1]*inv; gv.z = ex[2]*inv; gv.w = ex[3]*inv;
            *(float4*)&ggate[t4] = gv;
            atomicAdd(&lcnt[idxs[0]], 1); atomicAdd(&lcnt[idxs[1]], 1);
            atomicAdd(&lcnt[idxs[2]], 1); atomicAdd(&lcnt[idxs[3]], 1);
        }
    }
    __syncthreads();
    if (threadIdx.x < N_EXP && lcnt[threadIdx.x])
        atomicAdd(&counts[view * N_EXP + threadIdx.x], lcnt[threadIdx.x]);
}

// ------------------------------------------------------------------
// parallel scan + expert-affine XCD tile list. XCD x = (g&15)>>1 owns the
// group's tiles; slots s = x + 8*k (blockIdx%8 ~ XCD). Overflow -> spill tail.
// ------------------------------------------------------------------
__global__ void scan_kernel(const int* __restrict__ counts, int* __restrict__ offs,
                            int* __restrict__ cursor, int* __restrict__ tiles,
                            int* __restrict__ spillCnt) {
    __shared__ int ntS[NGROUP];
    int t = threadIdx.x;        // 64 threads
    if (t == 0) spillCnt[0] = 0;
    if (t < NGROUP) ntS[t] = (counts[t] + ROWS - 1) / ROWS;
    for (int s = t; s < NT_TOTAL; s += 64) tiles[s] = -1;
    __syncthreads();
    if (t <= NGROUP) {
        int acc = 0;
        for (int g = 0; g < t && g < NGROUP; g++) acc += counts[g];
        if (t < NGROUP) { offs[t] = acc; cursor[t] = acc; }
        else offs[NGROUP] = acc;
    }
    if (t < NGROUP) {
        int x = (t & 15) >> 1;      // expert pair -> XCD
        int kstart = 0;
        for (int g2 = 0; g2 < t; g2++)
            if (((g2 & 15) >> 1) == x) kstart += ntS[g2];
        int nt = ntS[t];
        for (int i = 0; i < nt; i++) {
            int k = kstart + i, rec = (t << 16) | i;
            if (k < NT_STRIPE / 8) tiles[x + 8 * k] = rec;
            else {
                int sp = atomicAdd(spillCnt, 1);
                if (sp < NT_SPILL) tiles[NT_STRIPE + sp] = rec;
            }
        }
    }
}

// ------------------------------------------------------------------
// fill: block = 256 tokens of one view; LDS-aggregated cursor claims
// ------------------------------------------------------------------
__global__ __launch_bounds__(256) void fill_kernel(const int* __restrict__ gidx,
                                                   const float* __restrict__ ggate,
                                                   int* __restrict__ cursor,
                                                   int* __restrict__ rowTok,
                                                   float* __restrict__ rowGate) {
    __shared__ int lc[N_EXP], lbase[N_EXP];
    int view = blockIdx.y;
    int token = blockIdx.x * 256 + threadIdx.x;
    if (threadIdx.x < N_EXP) lc[threadIdx.x] = 0;
    __syncthreads();
    size_t t4 = ((size_t)view * N_TOK + token) * TOPK;
    int4 e4 = *(const int4*)&gidx[t4];
    float4 g4 = *(const float4*)&ggate[t4];
    int e[4] = { e4.x, e4.y, e4.z, e4.w };
    float gg[4] = { g4.x, g4.y, g4.z, g4.w };
    int lp[4];
    #pragma unroll
    for (int k = 0; k < TOPK; k++) lp[k] = atomicAdd(&lc[e[k]], 1);
    __syncthreads();
    if (threadIdx.x < N_EXP)
        lbase[threadIdx.x] = lc[threadIdx.x] ? atomicAdd(&cursor[view * N_EXP + threadIdx.x], lc[threadIdx.x]) : 0;
    __syncthreads();
    #pragma unroll
    for (int k = 0; k < TOPK; k++) {
        int pos = lbase[e[k]] + lp[k];
        rowTok[pos] = token;
        rowGate[pos] = gg[k];
    }
}

// ------------------------------------------------------------------
// fused FFN, wave-specialized 32x32x16 pipeline.
// Waves 0-3 (G1): GEMM1(c) + gelu -> Hc[c&1];  waves 4-7 (G2): GEMM2(c-1).
// One persistent f32x16 st[4]: A-frags for G1 (bitcast), acc2 for G2.
// LDS = W1s 32K + W2s 32K + Hc 2x8K = 81920 B -> 2 blocks/CU.
// ------------------------------------------------------------------
__global__ __launch_bounds__(512, 4) void ffn_kernel(
    const unsigned short* __restrict__ Xbf, const unsigned short* __restrict__ Wf,
    const float* __restrict__ b1, const float* __restrict__ b2,
    const int* __restrict__ offs, const int* __restrict__ tiles,
    const int* __restrict__ rowTok, const float* __restrict__ rowGate,
    float* __restrict__ out)
{
    __shared__ __align__(16) unsigned short W1s[16384];     // 32 KB
    __shared__ __align__(16) unsigned short W2s[16384];     // 32 KB
    __shared__ __align__(16) unsigned short HcS[2][4096];   // 2 x 8 KB, C-order

    int rec = tiles[blockIdx.x];
    if (rec < 0) return;
    int g = rec >> 16, view = g >> 4, e = g & 15;
    int base = offs[g];
    int L = offs[g + 1] - base;
    int r0 = (rec & 0xffff) * ROWS;

    int tid = threadIdx.x;
    int wave = tid >> 6, lane = tid & 63;
    bool isG1 = wave < 4;
    int mt = wave & 1, nh = (wave >> 1) & 1;        // G1 roles: m-tile, n-half
    int u = wave & 3, ms = u & 1, ng = u >> 1;      // G2 roles: m-tile, n-quad

    const unsigned short* wchunk = Wf + (size_t)e * NCH * REC_ELTS;
    dma_half(wchunk, W1s, wave, lane);              // W1[0]

    f32x16 zz;
    #pragma unroll
    for (int i = 0; i < 16; i++) zz[i] = 0.f;

    f32x16 st[4];                                   // G1: A-frags; G2: acc2
    if (isG1) {
        int gr = r0 + mt * 32 + (lane & 31);
        int token = (gr < L) ? rowTok[base + gr] : 0;
        const unsigned short* xp = Xbf + ((size_t)view * N_TOK + token) * D_MODEL;
        int h = lane >> 5;
        #pragma unroll
        for (int kt = 0; kt < 16; kt++) {
            float4 x = *(const float4*)(xp + kt * 16 + h * 8);
            st[kt >> 2][(kt & 3) * 4 + 0] = x.x;
            st[kt >> 2][(kt & 3) * 4 + 1] = x.y;
            st[kt >> 2][(kt & 3) * 4 + 2] = x.z;
            st[kt >> 2][(kt & 3) * 4 + 3] = x.w;
        }
    } else {
        #pragma unroll
        for (int i = 0; i < 4; i++) st[i] = zz;
    }
    __syncthreads();            // W1[0] landed

    for (int c = 0; c <= NCH; c++) {
        if (isG1) {
            if (c < NCH) {
                // GEMM1(c): 32x32 tile (mt, nh), K=256, 2 ILP chains
                f32x16 a0 = zz, a1 = zz;
                #pragma unroll
                for (int kt = 0; kt < 16; kt += 2) {
                    float4 t0 = { st[kt >> 2][(kt & 3) * 4], st[kt >> 2][(kt & 3) * 4 + 1],
                                  st[kt >> 2][(kt & 3) * 4 + 2], st[kt >> 2][(kt & 3) * 4 + 3] };
                    s16x8 af0 = __builtin_bit_cast(s16x8, t0);
                    s16x8 b0 = *(const s16x8*)&W1s[((kt * 2 + nh) * 64 + lane) * 8];
                    a0 = __builtin_amdgcn_mfma_f32_32x32x16_bf16(af0, b0, a0, 0, 0, 0);
                    int k1 = kt + 1;
                    float4 t1 = { st[k1 >> 2][(k1 & 3) * 4], st[k1 >> 2][(k1 & 3) * 4 + 1],
                                  st[k1 >> 2][(k1 & 3) * 4 + 2], st[k1 >> 2][(k1 & 3) * 4 + 3] };
                    s16x8 af1 = __builtin_bit_cast(s16x8, t1);
                    s16x8 b1f = *(const s16x8*)&W1s[((k1 * 2 + nh) * 64 + lane) * 8];
                    a1 = __builtin_amdgcn_mfma_f32_32x32x16_bf16(af1, b1f, a1, 0, 0, 0);
                }
                float bb = b1[e * HDIM + c * CH + nh * 32 + (lane & 31)];
                unsigned short* hdst = &HcS[c & 1][((mt * 2 + nh) * 16) * 64 + lane];
                #pragma unroll
                for (int r = 0; r < 16; r++) {
                    float hv = a0[r] + a1[r] + bb;
                    float uu = hv * (0.7978845608f + 0.0356774081f * hv * hv);
                    float ex2 = __expf(2.f * uu);
                    float tn = 1.f - 2.f * __builtin_amdgcn_rcpf(1.f + ex2);
                    hdst[r * 64] = f2bf(0.5f * hv * (1.f + tn));
                }
            }
        } else {
            if (c > 0) {
                // GEMM2(c-1): rows ms*32, cols (ng*4..+4)*32, K=64
                int row = lane & 31, h = lane >> 5;
                int r_ = (row & 3) + 4 * (row >> 3);
                int w5 = (row >> 2) & 1;
                const unsigned short* hsrc = &HcS[(c - 1) & 1][0];
                #pragma unroll
                for (int kt2 = 0; kt2 < 4; kt2++) {
                    s16x8 a = *(const s16x8*)&hsrc[((ms * 2 + (kt2 >> 1)) * 16 + r_) * 64
                                                   + w5 * 32 + (kt2 & 1) * 16 + h * 8];
                    #pragma unroll
                    for (int nt = 0; nt < 4; nt++) {
                        s16x8 b = *(const s16x8*)&W2s[((kt2 * 8 + ng * 4 + nt) * 64 + lane) * 8];
                        st[nt] = __builtin_amdgcn_mfma_f32_32x32x16_bf16(a, b, st[nt], 0, 0, 0);
                    }
                }
            }
        }
        __syncthreads();    // G1 done with W1s; G2 done with W2s + Hc[(c-1)&1]
        if (c + 1 < NCH) dma_half(wchunk + (size_t)(c + 1) * REC_ELTS, W1s, wave, lane);
        if (c < NCH)     dma_half(wchunk + (size_t)c * REC_ELTS + 16384, W2s, wave, lane);
        __syncthreads();    // drains DMA; Hc[c&1] visible
    }

    // epilogue (G2 waves only): out[token] += gate * (acc2 + b2)
    if (!isG1) {
        #pragma unroll
        for (int nt = 0; nt < 4; nt++) {
            int col = (ng * 4 + nt) * 32 + (lane & 31);
            float b2v = b2[e * D_MODEL + col];
            #pragma unroll
            for (int r = 0; r < 16; r++) {
                int rloc = ms * 32 + (r & 3) + 8 * (r >> 2) + 4 * (lane >> 5);
                int gr = r0 + rloc;
                if (gr < L) {
                    int token = rowTok[base + gr];
                    float gate = rowGate[base + gr];
                    atomicAdd(&out[(size_t)token * D_MODEL + col], gate * (st[nt][r] + b2v));
                }
            }
        }
    }
}

// ------------------------------------------------------------------
extern "C" void kernel_launch(void* const* d_in, const int* in_sizes, int n_in,
                              void* d_out, int out_size, void* d_ws, size_t ws_size,
                              hipStream_t stream)
{
    const float* v0   = (const float*)d_in[0];
    const float* v1   = (const float*)d_in[1];
    const float* v2   = (const float*)d_in[2];
    const float* rw   = (const float*)d_in[3];
    const float* keys = (const float*)d_in[4];
    const float* W1   = (const float*)d_in[5];
    const float* b1   = (const float*)d_in[6];
    const float* W2   = (const float*)d_in[7];
    const float* b2   = (const float*)d_in[8];
    float* out = (float*)d_out;

    char* p = (char*)d_ws;
    unsigned short* Xbf = (unsigned short*)p; p += (size_t)N_VIEWS * N_TOK * D_MODEL * 2;
    unsigned short* Wf  = (unsigned short*)p; p += (size_t)N_EXP * NCH * REC_ELTS * 2;
    int*   counts = (int*)p;   p += 256;
    int*   offs   = (int*)p;   p += 256;
    int*   cursor = (int*)p;   p += 256;
    int*   spill  = (int*)p;   p += 256;
    int*   tiles  = (int*)p;   p += NT_TOTAL * 4 + 64;
    int*   gidx   = (int*)p;   p += (size_t)N_VIEWS * N_TOK * TOPK * 4;
    float* ggate  = (float*)p; p += (size_t)N_VIEWS * N_TOK * TOPK * 4;
    int*   rowTok = (int*)p;   p += (size_t)N_VIEWS * N_TOK * TOPK * 4;
    float* rowGate= (float*)p; p += (size_t)N_VIEWS * N_TOK * TOPK * 4;

    hipMemsetAsync(counts, 0, NGROUP * sizeof(int), stream);
    hipMemsetAsync(out, 0, (size_t)out_size * sizeof(float), stream);

    wfrag_kernel<<<dim3(NCH, N_EXP, 2), 256, 0, stream>>>(W1, W2, Wf);
    route_kernel<<<dim3(N_TOK / 64, N_VIEWS), 256, 0, stream>>>(v0, v1, v2, rw, keys, Xbf,
                                                                gidx, ggate, counts);
    scan_kernel<<<1, 64, 0, stream>>>(counts, offs, cursor, tiles, spill);
    fill_kernel<<<dim3(N_TOK / 256, N_VIEWS), 256, 0, stream>>>(gidx, ggate, cursor,
                                                                rowTok, rowGate);
    ffn_kernel<<<dim3(NT_TOTAL), 512, 0, stream>>>(Xbf, Wf, b1, b2, offs, tiles,
                                                   rowTok, rowGate, out);
}

// Round 7
// 416.049 us; speedup vs baseline: 1.0561x; 1.0561x over previous
//
#include <hip/hip_runtime.h>
#include <math.h>

#define D_MODEL 256
#define N_EXP   16
#define N_VIEWS 3
#define N_TOK   8192
#define TOPK    4
#define HDIM    1024
#define CH      64
#define NCH     16
#define ROWS    64             // rows per ffn tile
#define NGROUP  48
#define NT_STRIPE 2048         // 8 XCD lanes x 256 slots
#define NT_SPILL  512
#define NT_TOTAL  (NT_STRIPE + NT_SPILL)
#define REC_ELTS 32768         // chunk record: W1 half (16384) + W2 half (16384) shorts

typedef short s16x8 __attribute__((ext_vector_type(8)));
typedef float f32x4 __attribute__((ext_vector_type(4)));

__device__ __forceinline__ unsigned short f2bf(float x) {
    union { float f; unsigned u; } a; a.f = x;
    unsigned r = a.u + 0x7FFFu + ((a.u >> 16) & 1u);   // RNE
    return (unsigned short)(r >> 16);
}

// async global -> LDS, 16 B per lane; LDS dst is wave-uniform base + lane*16
__device__ __forceinline__ void dma16(const unsigned short* gp, unsigned short* lp) {
    __builtin_amdgcn_global_load_lds(
        (const __attribute__((address_space(1))) unsigned int*)gp,
        (__attribute__((address_space(3))) unsigned int*)lp, 16, 0, 0);
}

// stage one 32 KB half-record: 8 waves x 4 instr x 1 KB
__device__ __forceinline__ void dma_half(const unsigned short* gsrc, unsigned short* ldst,
                                         int wave, int lane) {
    #pragma unroll
    for (int i = 0; i < 4; i++) {
        int blk = wave * 4 + i;                       // 0..31, 1 KB blocks
        dma16(gsrc + ((size_t)blk * 64 + lane) * 8, ldst + blk * 512);
    }
}

// ------------------------------------------------------------------
// fused prep: blocks [0,512) build Wf fragment records (wfrag role);
// blocks [512,896) do routing (route role). Independent work, one launch.
//
// W1 half: idx=(ks*4+nt)*64+lane : elem = W1[e][ks*32+(lane>>4)*8+j][c*64+nt*16+(lane&15)]
// W2 half: idx=(ks2*16+nt)*64+lane: elem = W2[e][c*64+ks2*32+(lane>>4)*8+j][nt*16+(lane&15)]
// ------------------------------------------------------------------
__global__ __launch_bounds__(256) void prep_kernel(
    const float* __restrict__ v0, const float* __restrict__ v1, const float* __restrict__ v2,
    const float* __restrict__ rw, const float* __restrict__ keys,
    const float* __restrict__ W1, const float* __restrict__ W2,
    unsigned short* __restrict__ Wf, unsigned short* __restrict__ Xbf,
    int* __restrict__ gidx, float* __restrict__ ggate, int* __restrict__ counts)
{
    __shared__ __align__(16) float cwS[N_EXP * D_MODEL];
    __shared__ float knS[N_EXP];
    __shared__ int lcnt[N_EXP];

    int bid = blockIdx.x;
    if (bid < 512) {
        // ---- wfrag role ----
        int c = bid & 15, e = (bid >> 4) & 15, z = bid >> 8;
        unsigned short* dst = Wf + (size_t)(e * NCH + c) * REC_ELTS;
        if (z == 0) {
            const float* src = W1 + (size_t)e * 256 * 1024;
            #pragma unroll
            for (int i = 0; i < 8; i++) {
                int idx = threadIdx.x + i * 256;
                int lane = idx & 63, nt = (idx >> 6) & 3, ks = idx >> 8;
                int ncol = c * 64 + nt * 16 + (lane & 15);
                int kbase = ks * 32 + (lane >> 4) * 8;
                s16x8 o;
                #pragma unroll
                for (int j = 0; j < 8; j++) o[j] = (short)f2bf(src[(size_t)(kbase + j) * 1024 + ncol]);
                *(s16x8*)(dst + (size_t)idx * 8) = o;
            }
        } else {
            const float* src = W2 + (size_t)e * 1024 * 256;
            dst += 16384;
            #pragma unroll
            for (int i = 0; i < 8; i++) {
                int idx = threadIdx.x + i * 256;
                int lane = idx & 63, ntile = (idx >> 6) & 15, ks2 = idx >> 10;
                int n = ntile * 16 + (lane & 15);
                int kbase = c * 64 + ks2 * 32 + (lane >> 4) * 8;
                s16x8 o;
                #pragma unroll
                for (int j = 0; j < 8; j++) o[j] = (short)f2bf(src[(size_t)(kbase + j) * 256 + n]);
                *(s16x8*)(dst + (size_t)idx * 8) = o;
            }
        }
        return;
    }

    // ---- route role ----
    int rb = bid - 512;
    int view = rb >> 7, xb = rb & 127;
    const float* src = view == 0 ? v0 : (view == 1 ? v1 : v2);
    for (int i = threadIdx.x; i < N_EXP * D_MODEL; i += 256)
        cwS[i] = rw[view * N_EXP * D_MODEL + i] + 2.0f * keys[i];
    if (threadIdx.x < N_EXP) {
        const float4* kp = (const float4*)(keys + threadIdx.x * D_MODEL);
        float s = 0.f;
        for (int d = 0; d < 64; d++) { float4 k = kp[d]; s += k.x*k.x + k.y*k.y + k.z*k.z + k.w*k.w; }
        knS[threadIdx.x] = s; lcnt[threadIdx.x] = 0;
    }
    __syncthreads();

    int wave = threadIdx.x >> 6, lane = threadIdx.x & 63;
    for (int t = 0; t < 16; t++) {
        int token = xb * 64 + wave * 16 + t;
        float4 v = ((const float4*)(src + (size_t)token * D_MODEL))[lane];
        ushort4 xo; xo.x = f2bf(v.x); xo.y = f2bf(v.y); xo.z = f2bf(v.z); xo.w = f2bf(v.w);
        ((ushort4*)(Xbf + ((size_t)view * N_TOK + token) * D_MODEL))[lane] = xo;
        float lg[N_EXP];
        #pragma unroll
        for (int e = 0; e < N_EXP; e++) {
            float4 w = *(const float4*)&cwS[e * D_MODEL + lane * 4];
            float p = v.x * w.x + v.y * w.y + v.z * w.z + v.w * w.w;
            #pragma unroll
            for (int s = 32; s > 0; s >>= 1) p += __shfl_xor(p, s, 64);
            lg[e] = p - knS[e];
        }
        int idxs[TOPK]; float vals[TOPK];
        #pragma unroll
        for (int k = 0; k < TOPK; k++) {
            float best = -1e30f; int bi = 0;
            #pragma unroll
            for (int e = 0; e < N_EXP; e++)
                if (lg[e] > best) { best = lg[e]; bi = e; }
            idxs[k] = bi; vals[k] = best;
            #pragma unroll
            for (int e = 0; e < N_EXP; e++)
                lg[e] = (e == bi) ? -1e30f : lg[e];
        }
        float m = vals[0], s = 0.f, ex[TOPK];
        #pragma unroll
        for (int k = 0; k < TOPK; k++) { ex[k] = __expf(vals[k] - m); s += ex[k]; }
        float inv = 1.0f / s;
        if (lane == 0) {
            size_t t4 = ((size_t)view * N_TOK + token) * TOPK;
            int4 gi; gi.x = idxs[0]; gi.y = idxs[1]; gi.z = idxs[2]; gi.w = idxs[3];
            *(int4*)&gidx[t4] = gi;
            float4 gv; gv.x = ex[0]*inv; gv.y = ex[1]*inv; gv.z = ex[2]*inv; gv.w = ex[3]*inv;
            *(float4*)&ggate[t4] = gv;
            atomicAdd(&lcnt[idxs[0]], 1); atomicAdd(&lcnt[idxs[1]], 1);
            atomicAdd(&lcnt[idxs[2]], 1); atomicAdd(&lcnt[idxs[3]], 1);
        }
    }
    __syncthreads();
    if (threadIdx.x < N_EXP && lcnt[threadIdx.x])
        atomicAdd(&counts[view * N_EXP + threadIdx.x], lcnt[threadIdx.x]);
}

// ------------------------------------------------------------------
// parallel scan + expert-affine XCD tile list. XCD x = (g&15)>>1 owns the
// group's tiles; slots s = x + 8*k (blockIdx%8 ~ XCD). Overflow -> spill tail.
// ------------------------------------------------------------------
__global__ void scan_kernel(const int* __restrict__ counts, int* __restrict__ offs,
                            int* __restrict__ cursor, int* __restrict__ tiles,
                            int* __restrict__ spillCnt) {
    __shared__ int ntS[NGROUP];
    int t = threadIdx.x;        // 64 threads
    if (t == 0) spillCnt[0] = 0;
    if (t < NGROUP) ntS[t] = (counts[t] + ROWS - 1) / ROWS;
    for (int s = t; s < NT_TOTAL; s += 64) tiles[s] = -1;
    __syncthreads();
    if (t <= NGROUP) {
        int acc = 0;
        for (int g = 0; g < t && g < NGROUP; g++) acc += counts[g];
        if (t < NGROUP) { offs[t] = acc; cursor[t] = acc; }
        else offs[NGROUP] = acc;
    }
    if (t < NGROUP) {
        int x = (t & 15) >> 1;      // expert pair -> XCD
        int kstart = 0;
        for (int g2 = 0; g2 < t; g2++)
            if (((g2 & 15) >> 1) == x) kstart += ntS[g2];
        int nt = ntS[t];
        for (int i = 0; i < nt; i++) {
            int k = kstart + i, rec = (t << 16) | i;
            if (k < NT_STRIPE / 8) tiles[x + 8 * k] = rec;
            else {
                int sp = atomicAdd(spillCnt, 1);
                if (sp < NT_SPILL) tiles[NT_STRIPE + sp] = rec;
            }
        }
    }
}

// ------------------------------------------------------------------
// fill: block = 256 tokens of one view; LDS-aggregated cursor claims
// ------------------------------------------------------------------
__global__ __launch_bounds__(256) void fill_kernel(const int* __restrict__ gidx,
                                                   const float* __restrict__ ggate,
                                                   int* __restrict__ cursor,
                                                   int* __restrict__ rowTok,
                                                   float* __restrict__ rowGate) {
    __shared__ int lc[N_EXP], lbase[N_EXP];
    int view = blockIdx.y;
    int token = blockIdx.x * 256 + threadIdx.x;
    if (threadIdx.x < N_EXP) lc[threadIdx.x] = 0;
    __syncthreads();
    size_t t4 = ((size_t)view * N_TOK + token) * TOPK;
    int4 e4 = *(const int4*)&gidx[t4];
    float4 g4 = *(const float4*)&ggate[t4];
    int e[4] = { e4.x, e4.y, e4.z, e4.w };
    float gg[4] = { g4.x, g4.y, g4.z, g4.w };
    int lp[4];
    #pragma unroll
    for (int k = 0; k < TOPK; k++) lp[k] = atomicAdd(&lc[e[k]], 1);
    __syncthreads();
    if (threadIdx.x < N_EXP)
        lbase[threadIdx.x] = lc[threadIdx.x] ? atomicAdd(&cursor[view * N_EXP + threadIdx.x], lc[threadIdx.x]) : 0;
    __syncthreads();
    #pragma unroll
    for (int k = 0; k < TOPK; k++) {
        int pos = lbase[e[k]] + lp[k];
        rowTok[pos] = token;
        rowGate[pos] = gg[k];
    }
}

// ------------------------------------------------------------------
// fused FFN: 1 block = 64 rows of one (view,expert) group; 512 thr, 8 waves.
// r5 structure, GEMM1 re-blocked to 2m x 1n per wave: each W1 B-frag read
// once per wave (B-read traffic halved); A held in regs (areg[2][8], 64 VGPR;
// acc in AGPRs). LDS 74240 B -> 2 blocks/CU. DMA one phase ahead, 2 barriers.
// ------------------------------------------------------------------
__global__ __launch_bounds__(512, 4) void ffn_kernel(
    const unsigned short* __restrict__ Xbf, const unsigned short* __restrict__ Wf,
    const float* __restrict__ b1, const float* __restrict__ b2,
    const int* __restrict__ offs, const int* __restrict__ tiles,
    const int* __restrict__ rowTok, const float* __restrict__ rowGate,
    float* __restrict__ out)
{
    __shared__ __align__(16) unsigned short Wbuf[REC_ELTS];   // 64 KB: W1c | W2c
    __shared__ __align__(16) unsigned short Hc[ROWS * CH];    // 8 KB, A-frag order
    __shared__ int   tokS[ROWS];
    __shared__ float gateS[ROWS];

    int rec = tiles[blockIdx.x];
    if (rec < 0) return;
    int g = rec >> 16, view = g >> 4, e = g & 15;
    int base = offs[g];
    int L = offs[g + 1] - base;
    int r0 = (rec & 0xffff) * ROWS;

    int tid = threadIdx.x;
    int wave = tid >> 6, lane = tid & 63, lmod = lane & 15, quad = lane >> 4;

    const unsigned short* wchunk = Wf + (size_t)e * NCH * REC_ELTS;
    dma_half(wchunk, Wbuf, wave, lane);          // W1[0]

    if (tid < ROWS) {
        int gr = r0 + tid; bool ok = gr < L;
        tokS[tid]  = ok ? rowTok[base + gr] : -1;
        gateS[tid] = ok ? rowGate[base + gr] : 0.f;
    }

    int mh  = wave & 1, nt1 = wave >> 1;         // GEMM1 roles: m-half (2 tiles), n-tile
    int ms  = wave & 1, ns  = wave >> 1;         // GEMM2 roles: 2 m-tiles, 4 n-tiles

    __syncthreads();   // tokS ready; W1[0] landed (barrier drains vmcnt)

    // X A-fragments for m-tiles mh*2+{0,1} (64 VGPR)
    s16x8 areg[2][8];
    #pragma unroll
    for (int mt2 = 0; mt2 < 2; mt2++) {
        int token = tokS[(mh * 2 + mt2) * 16 + lmod];
        if (token < 0) token = 0;
        const unsigned short* xp = Xbf + ((size_t)view * N_TOK + token) * D_MODEL;
        #pragma unroll
        for (int ks = 0; ks < 8; ks++)
            areg[mt2][ks] = *(const s16x8*)(xp + ks * 32 + quad * 8);
    }
    dma_half(wchunk + 16384, Wbuf + 16384, wave, lane);   // W2[0], lands during GEMM1[0]

    f32x4 acc2[2][4];
    #pragma unroll
    for (int i = 0; i < 2; i++)
        #pragma unroll
        for (int j = 0; j < 4; j++) acc2[i][j] = (f32x4){0.f, 0.f, 0.f, 0.f};

    for (int c = 0; c < NCH; c++) {
        // ---- GEMM1: 32 rows x 16 cols per wave, K=256; B-frag read ONCE
        f32x4 acc1[2];
        acc1[0] = (f32x4){0.f, 0.f, 0.f, 0.f};
        acc1[1] = (f32x4){0.f, 0.f, 0.f, 0.f};
        #pragma unroll
        for (int ks = 0; ks < 8; ks++) {
            s16x8 b = *(const s16x8*)&Wbuf[((ks * 4 + nt1) * 64 + lane) * 8];
            acc1[0] = __builtin_amdgcn_mfma_f32_16x16x32_bf16(areg[0][ks], b, acc1[0], 0, 0, 0);
            acc1[1] = __builtin_amdgcn_mfma_f32_16x16x32_bf16(areg[1][ks], b, acc1[1], 0, 0, 0);
        }
        // ---- bias + gelu -> Hc (A-frag order for GEMM2)
        {
            float bb = b1[e * HDIM + c * CH + nt1 * 16 + lmod];
            int kh = nt1 >> 1;                        // col>>5
            int qa = (nt1 & 1) * 2 + (lmod >> 3);     // (col&31)>>3
            #pragma unroll
            for (int mt2 = 0; mt2 < 2; mt2++) {
                int baseo = (((mh * 2 + mt2) * 2 + kh) * 64 + qa * 16 + quad * 4) * 8 + (lmod & 7);
                #pragma unroll
                for (int r = 0; r < 4; r++) {
                    float h = acc1[mt2][r] + bb;
                    float u = h * (0.7978845608f + 0.0356774081f * h * h);
                    float ex2 = __expf(2.f * u);
                    float tn = 1.f - 2.f * __builtin_amdgcn_rcpf(1.f + ex2);
                    Hc[baseo + r * 8] = f2bf(0.5f * h * (1.f + tn));
                }
            }
        }
        __syncthreads();   // drains W2[c] DMA; Hc visible; GEMM1 done with W1 half
        if (c < NCH - 1)   // W1[c+1] (lands during GEMM2)
            dma_half(wchunk + (size_t)(c + 1) * REC_ELTS, Wbuf, wave, lane);
        // ---- GEMM2: 32 rows x 64 cols per wave, K=64
        #pragma unroll
        for (int ks2 = 0; ks2 < 2; ks2++) {
            s16x8 afr[2];
            #pragma unroll
            for (int mt = 0; mt < 2; mt++)
                afr[mt] = *(const s16x8*)&Hc[(((ms * 2 + mt) * 2 + ks2) * 64 + lane) * 8];
            #pragma unroll
            for (int nt = 0; nt < 4; nt++) {
                s16x8 b = *(const s16x8*)&Wbuf[16384 + ((ks2 * 16 + ns * 4 + nt) * 64 + lane) * 8];
                #pragma unroll
                for (int mt = 0; mt < 2; mt++)
                    acc2[mt][nt] = __builtin_amdgcn_mfma_f32_16x16x32_bf16(
                        afr[mt], b, acc2[mt][nt], 0, 0, 0);
            }
        }
        __syncthreads();   // drains W1[c+1] DMA; GEMM2 done with W2 half + Hc
        if (c < NCH - 1)   // W2[c+1] (lands during GEMM1[c+1]+gelu)
            dma_half(wchunk + (size_t)(c + 1) * REC_ELTS + 16384, Wbuf + 16384, wave, lane);
    }

    // epilogue: out[token] += gate * (acc2 + b2)
    #pragma unroll
    for (int nt = 0; nt < 4; nt++) {
        int col = (ns * 4 + nt) * 16 + lmod;
        float b2v = b2[e * D_MODEL + col];
        #pragma unroll
        for (int mt = 0; mt < 2; mt++) {
            #pragma unroll
            for (int r = 0; r < 4; r++) {
                int rloc = (ms * 2 + mt) * 16 + quad * 4 + r;
                if (r0 + rloc < L) {
                    atomicAdd(&out[(size_t)tokS[rloc] * D_MODEL + col],
                              gateS[rloc] * (acc2[mt][nt][r] + b2v));
                }
            }
        }
    }
}

// ------------------------------------------------------------------
extern "C" void kernel_launch(void* const* d_in, const int* in_sizes, int n_in,
                              void* d_out, int out_size, void* d_ws, size_t ws_size,
                              hipStream_t stream)
{
    const float* v0   = (const float*)d_in[0];
    const float* v1   = (const float*)d_in[1];
    const float* v2   = (const float*)d_in[2];
    const float* rw   = (const float*)d_in[3];
    const float* keys = (const float*)d_in[4];
    const float* W1   = (const float*)d_in[5];
    const float* b1   = (const float*)d_in[6];
    const float* W2   = (const float*)d_in[7];
    const float* b2   = (const float*)d_in[8];
    float* out = (float*)d_out;

    char* p = (char*)d_ws;
    unsigned short* Xbf = (unsigned short*)p; p += (size_t)N_VIEWS * N_TOK * D_MODEL * 2;
    unsigned short* Wf  = (unsigned short*)p; p += (size_t)N_EXP * NCH * REC_ELTS * 2;
    int*   counts = (int*)p;   p += 256;
    int*   offs   = (int*)p;   p += 256;
    int*   cursor = (int*)p;   p += 256;
    int*   spill  = (int*)p;   p += 256;
    int*   tiles  = (int*)p;   p += NT_TOTAL * 4 + 64;
    int*   gidx   = (int*)p;   p += (size_t)N_VIEWS * N_TOK * TOPK * 4;
    float* ggate  = (float*)p; p += (size_t)N_VIEWS * N_TOK * TOPK * 4;
    int*   rowTok = (int*)p;   p += (size_t)N_VIEWS * N_TOK * TOPK * 4;
    float* rowGate= (float*)p; p += (size_t)N_VIEWS * N_TOK * TOPK * 4;

    hipMemsetAsync(counts, 0, NGROUP * sizeof(int), stream);
    hipMemsetAsync(out, 0, (size_t)out_size * sizeof(float), stream);

    prep_kernel<<<896, 256, 0, stream>>>(v0, v1, v2, rw, keys, W1, W2,
                                         Wf, Xbf, gidx, ggate, counts);
    scan_kernel<<<1, 64, 0, stream>>>(counts, offs, cursor, tiles, spill);
    fill_kernel<<<dim3(N_TOK / 256, N_VIEWS), 256, 0, stream>>>(gidx, ggate, cursor,
                                                                rowTok, rowGate);
    ffn_kernel<<<dim3(NT_TOTAL), 512, 0, stream>>>(Xbf, Wf, b1, b2, offs, tiles,
                                                   rowTok, rowGate, out);
}

// Round 8
// 391.544 us; speedup vs baseline: 1.1222x; 1.0626x over previous
//
#include <hip/hip_runtime.h>
#include <math.h>

#define D_MODEL 256
#define N_EXP   16
#define N_VIEWS 3
#define N_TOK   8192
#define TOPK    4
#define HDIM    1024
#define CH      64
#define NCH     16
#define ROWS    64             // rows per ffn tile
#define NGROUP  48
#define NT_STRIPE 2048         // 8 XCD lanes x 256 slots
#define NT_SPILL  512
#define NT_TOTAL  (NT_STRIPE + NT_SPILL)
#define REC_ELTS 32768         // chunk record: W1 half (16384) + W2 half (16384) shorts

typedef short s16x8 __attribute__((ext_vector_type(8)));
typedef float f32x4 __attribute__((ext_vector_type(4)));

__device__ __forceinline__ unsigned short f2bf(float x) {
    union { float f; unsigned u; } a; a.f = x;
    unsigned r = a.u + 0x7FFFu + ((a.u >> 16) & 1u);   // RNE
    return (unsigned short)(r >> 16);
}

// async global -> LDS, 16 B per lane; LDS dst is wave-uniform base + lane*16
__device__ __forceinline__ void dma16(const unsigned short* gp, unsigned short* lp) {
    __builtin_amdgcn_global_load_lds(
        (const __attribute__((address_space(1))) unsigned int*)gp,
        (__attribute__((address_space(3))) unsigned int*)lp, 16, 0, 0);
}

// stage one 32 KB half-record: 8 waves x 4 instr x 1 KB
__device__ __forceinline__ void dma_half(const unsigned short* gsrc, unsigned short* ldst,
                                         int wave, int lane) {
    #pragma unroll
    for (int i = 0; i < 4; i++) {
        int blk = wave * 4 + i;                       // 0..31, 1 KB blocks
        dma16(gsrc + ((size_t)blk * 64 + lane) * 8, ldst + blk * 512);
    }
}

// ------------------------------------------------------------------
// fused prep: blocks [0,512) build Wf fragment records via coalesced
// LDS-transpose (wfrag role); blocks [512,896) do routing (route role).
//
// W1 half: idx=(ks*4+nt)*64+lane : elem = W1[e][ks*32+(lane>>4)*8+j][c*64+nt*16+(lane&15)]
// W2 half: idx=(ks2*16+nt)*64+lane: elem = W2[e][c*64+ks2*32+(lane>>4)*8+j][nt*16+(lane&15)]
// ------------------------------------------------------------------
#define T1_STRIDE 65    // 256 x 65 f32 = 66560 B
#define T2_STRIDE 257   // 64 x 257 f32 = 65792 B

__global__ __launch_bounds__(256) void prep_kernel(
    const float* __restrict__ v0, const float* __restrict__ v1, const float* __restrict__ v2,
    const float* __restrict__ rw, const float* __restrict__ keys,
    const float* __restrict__ W1, const float* __restrict__ W2,
    unsigned short* __restrict__ Wf, unsigned short* __restrict__ Xbf,
    int* __restrict__ gidx, float* __restrict__ ggate, int* __restrict__ counts)
{
    __shared__ __align__(16) char smem[256 * T1_STRIDE * 4];   // 66560 B, role-unioned

    int bid = blockIdx.x;
    int tid = threadIdx.x;
    if (bid < 512) {
        // ---- wfrag role ----
        int c = bid & 15, e = (bid >> 4) & 15, z = bid >> 8;
        unsigned short* dst = Wf + (size_t)(e * NCH + c) * REC_ELTS;
        if (z == 0) {
            // stage W1 slab [k=256][nl=64] coalesced: 16 rows/pass, float4
            float* T1 = (float*)smem;
            const float* src = W1 + (size_t)e * 256 * 1024 + c * 64;
            #pragma unroll
            for (int p = 0; p < 16; p++) {
                int k = p * 16 + (tid >> 4), c4 = (tid & 15) * 4;
                float4 v = *(const float4*)(src + (size_t)k * 1024 + c4);
                T1[k * T1_STRIDE + c4]     = v.x;
                T1[k * T1_STRIDE + c4 + 1] = v.y;
                T1[k * T1_STRIDE + c4 + 2] = v.z;
                T1[k * T1_STRIDE + c4 + 3] = v.w;
            }
            __syncthreads();
            #pragma unroll
            for (int i = 0; i < 8; i++) {
                int idx = tid + i * 256;
                int lane = idx & 63, nt = (idx >> 6) & 3, ks = idx >> 8;
                int nl = nt * 16 + (lane & 15);
                int kbase = ks * 32 + (lane >> 4) * 8;
                s16x8 o;
                #pragma unroll
                for (int j = 0; j < 8; j++) o[j] = (short)f2bf(T1[(kbase + j) * T1_STRIDE + nl]);
                *(s16x8*)(dst + (size_t)idx * 8) = o;
            }
        } else {
            // stage W2 slab [k2l=64][n=256] coalesced: 4 rows/pass, float4
            float* T2 = (float*)smem;
            const float* src = W2 + ((size_t)e * 1024 + c * 64) * 256;
            #pragma unroll
            for (int p = 0; p < 16; p++) {
                int k2l = p * 4 + (tid >> 6), c4 = (tid & 63) * 4;
                float4 v = *(const float4*)(src + (size_t)k2l * 256 + c4);
                T2[k2l * T2_STRIDE + c4]     = v.x;
                T2[k2l * T2_STRIDE + c4 + 1] = v.y;
                T2[k2l * T2_STRIDE + c4 + 2] = v.z;
                T2[k2l * T2_STRIDE + c4 + 3] = v.w;
            }
            __syncthreads();
            dst += 16384;
            #pragma unroll
            for (int i = 0; i < 8; i++) {
                int idx = tid + i * 256;
                int lane = idx & 63, ntile = (idx >> 6) & 15, ks2 = idx >> 10;
                int n = ntile * 16 + (lane & 15);
                int kbase = ks2 * 32 + (lane >> 4) * 8;
                s16x8 o;
                #pragma unroll
                for (int j = 0; j < 8; j++) o[j] = (short)f2bf(T2[(kbase + j) * T2_STRIDE + n]);
                *(s16x8*)(dst + (size_t)idx * 8) = o;
            }
        }
        return;
    }

    // ---- route role ----
    float* cwS = (float*)smem;                       // 16 KB
    float* knS = (float*)(smem + 16384);             // 64 B
    int*  lcnt = (int*)(smem + 16384 + 64);          // 64 B
    int rb = bid - 512;
    int view = rb >> 7, xb = rb & 127;
    const float* src = view == 0 ? v0 : (view == 1 ? v1 : v2);
    for (int i = tid; i < N_EXP * D_MODEL; i += 256)
        cwS[i] = rw[view * N_EXP * D_MODEL + i] + 2.0f * keys[i];
    if (tid < N_EXP) {
        const float4* kp = (const float4*)(keys + tid * D_MODEL);
        float s = 0.f;
        for (int d = 0; d < 64; d++) { float4 k = kp[d]; s += k.x*k.x + k.y*k.y + k.z*k.z + k.w*k.w; }
        knS[tid] = s; lcnt[tid] = 0;
    }
    __syncthreads();

    int wave = tid >> 6, lane = tid & 63;
    for (int t = 0; t < 16; t++) {
        int token = xb * 64 + wave * 16 + t;
        float4 v = ((const float4*)(src + (size_t)token * D_MODEL))[lane];
        ushort4 xo; xo.x = f2bf(v.x); xo.y = f2bf(v.y); xo.z = f2bf(v.z); xo.w = f2bf(v.w);
        ((ushort4*)(Xbf + ((size_t)view * N_TOK + token) * D_MODEL))[lane] = xo;
        float lg[N_EXP];
        #pragma unroll
        for (int e = 0; e < N_EXP; e++) {
            float4 w = *(const float4*)&cwS[e * D_MODEL + lane * 4];
            float p = v.x * w.x + v.y * w.y + v.z * w.z + v.w * w.w;
            #pragma unroll
            for (int s = 32; s > 0; s >>= 1) p += __shfl_xor(p, s, 64);
            lg[e] = p - knS[e];
        }
        int idxs[TOPK]; float vals[TOPK];
        #pragma unroll
        for (int k = 0; k < TOPK; k++) {
            float best = -1e30f; int bi = 0;
            #pragma unroll
            for (int e = 0; e < N_EXP; e++)
                if (lg[e] > best) { best = lg[e]; bi = e; }
            idxs[k] = bi; vals[k] = best;
            #pragma unroll
            for (int e = 0; e < N_EXP; e++)
                lg[e] = (e == bi) ? -1e30f : lg[e];
        }
        float m = vals[0], s = 0.f, ex[TOPK];
        #pragma unroll
        for (int k = 0; k < TOPK; k++) { ex[k] = __expf(vals[k] - m); s += ex[k]; }
        float inv = 1.0f / s;
        if (lane == 0) {
            size_t t4 = ((size_t)view * N_TOK + token) * TOPK;
            int4 gi; gi.x = idxs[0]; gi.y = idxs[1]; gi.z = idxs[2]; gi.w = idxs[3];
            *(int4*)&gidx[t4] = gi;
            float4 gv; gv.x = ex[0]*inv; gv.y = ex[1]*inv; gv.z = ex[2]*inv; gv.w = ex[3]*inv;
            *(float4*)&ggate[t4] = gv;
            atomicAdd(&lcnt[idxs[0]], 1); atomicAdd(&lcnt[idxs[1]], 1);
            atomicAdd(&lcnt[idxs[2]], 1); atomicAdd(&lcnt[idxs[3]], 1);
        }
    }
    __syncthreads();
    if (tid < N_EXP && lcnt[tid])
        atomicAdd(&counts[view * N_EXP + tid], lcnt[tid]);
}

// ------------------------------------------------------------------
// parallel scan + expert-affine XCD tile list. XCD x = (g&15)>>1 owns the
// group's tiles; slots s = x + 8*k (blockIdx%8 ~ XCD). Overflow -> spill tail.
// ------------------------------------------------------------------
__global__ void scan_kernel(const int* __restrict__ counts, int* __restrict__ offs,
                            int* __restrict__ cursor, int* __restrict__ tiles,
                            int* __restrict__ spillCnt) {
    __shared__ int ntS[NGROUP];
    int t = threadIdx.x;        // 64 threads
    if (t == 0) spillCnt[0] = 0;
    if (t < NGROUP) ntS[t] = (counts[t] + ROWS - 1) / ROWS;
    for (int s = t; s < NT_TOTAL; s += 64) tiles[s] = -1;
    __syncthreads();
    if (t <= NGROUP) {
        int acc = 0;
        for (int g = 0; g < t && g < NGROUP; g++) acc += counts[g];
        if (t < NGROUP) { offs[t] = acc; cursor[t] = acc; }
        else offs[NGROUP] = acc;
    }
    if (t < NGROUP) {
        int x = (t & 15) >> 1;      // expert pair -> XCD
        int kstart = 0;
        for (int g2 = 0; g2 < t; g2++)
            if (((g2 & 15) >> 1) == x) kstart += ntS[g2];
        int nt = ntS[t];
        for (int i = 0; i < nt; i++) {
            int k = kstart + i, rec = (t << 16) | i;
            if (k < NT_STRIPE / 8) tiles[x + 8 * k] = rec;
            else {
                int sp = atomicAdd(spillCnt, 1);
                if (sp < NT_SPILL) tiles[NT_STRIPE + sp] = rec;
            }
        }
    }
}

// ------------------------------------------------------------------
// fill: block = 256 tokens of one view; LDS-aggregated cursor claims
// ------------------------------------------------------------------
__global__ __launch_bounds__(256) void fill_kernel(const int* __restrict__ gidx,
                                                   const float* __restrict__ ggate,
                                                   int* __restrict__ cursor,
                                                   int* __restrict__ rowTok,
                                                   float* __restrict__ rowGate) {
    __shared__ int lc[N_EXP], lbase[N_EXP];
    int view = blockIdx.y;
    int token = blockIdx.x * 256 + threadIdx.x;
    if (threadIdx.x < N_EXP) lc[threadIdx.x] = 0;
    __syncthreads();
    size_t t4 = ((size_t)view * N_TOK + token) * TOPK;
    int4 e4 = *(const int4*)&gidx[t4];
    float4 g4 = *(const float4*)&ggate[t4];
    int e[4] = { e4.x, e4.y, e4.z, e4.w };
    float gg[4] = { g4.x, g4.y, g4.z, g4.w };
    int lp[4];
    #pragma unroll
    for (int k = 0; k < TOPK; k++) lp[k] = atomicAdd(&lc[e[k]], 1);
    __syncthreads();
    if (threadIdx.x < N_EXP)
        lbase[threadIdx.x] = lc[threadIdx.x] ? atomicAdd(&cursor[view * N_EXP + threadIdx.x], lc[threadIdx.x]) : 0;
    __syncthreads();
    #pragma unroll
    for (int k = 0; k < TOPK; k++) {
        int pos = lbase[e[k]] + lp[k];
        rowTok[pos] = token;
        rowGate[pos] = gg[k];
    }
}

// ------------------------------------------------------------------
// fused FFN (r5 structure, proven 239 us / no spill): 1 block = 64 rows of one
// (view,expert) group; 512 thr, 8 waves. areg[8]=32 VGPR, acc2=32 AGPR.
// LDS 74240 B -> 2 blocks/CU. Async DMA one phase ahead, 2 barriers/chunk.
// GEMM1: wave = m-tile (wave&3) x n-half (wave>>2).
// GEMM2: wave = 2 m-tiles (wave&1) x 4 n-tiles (wave>>1).
// NOTE r7 lesson: 2-m-tile GEMM1 (areg[2][8]) exceeds the 128-reg cap -> spill.
// ------------------------------------------------------------------
__global__ __launch_bounds__(512, 4) void ffn_kernel(
    const unsigned short* __restrict__ Xbf, const unsigned short* __restrict__ Wf,
    const float* __restrict__ b1, const float* __restrict__ b2,
    const int* __restrict__ offs, const int* __restrict__ tiles,
    const int* __restrict__ rowTok, const float* __restrict__ rowGate,
    float* __restrict__ out)
{
    __shared__ __align__(16) unsigned short Wbuf[REC_ELTS];   // 64 KB: W1c | W2c
    __shared__ __align__(16) unsigned short Hc[ROWS * CH];    // 8 KB, A-frag order
    __shared__ int   tokS[ROWS];
    __shared__ float gateS[ROWS];

    int rec = tiles[blockIdx.x];
    if (rec < 0) return;
    int g = rec >> 16, view = g >> 4, e = g & 15;
    int base = offs[g];
    int L = offs[g + 1] - base;
    int r0 = (rec & 0xffff) * ROWS;

    int tid = threadIdx.x;
    int wave = tid >> 6, lane = tid & 63, lmod = lane & 15, quad = lane >> 4;

    const unsigned short* wchunk = Wf + (size_t)e * NCH * REC_ELTS;
    dma_half(wchunk, Wbuf, wave, lane);          // W1[0]

    if (tid < ROWS) {
        int gr = r0 + tid; bool ok = gr < L;
        tokS[tid]  = ok ? rowTok[base + gr] : -1;
        gateS[tid] = ok ? rowGate[base + gr] : 0.f;
    }

    int mt1 = wave & 3, nh = wave >> 2;          // GEMM1 roles
    int ms  = wave & 1, ns = wave >> 1;          // GEMM2 roles

    __syncthreads();   // tokS ready; W1[0] landed (barrier drains vmcnt)

    // X A-fragments for m-tile mt1 (32 VGPR)
    s16x8 areg[8];
    {
        int token = tokS[mt1 * 16 + lmod];
        if (token < 0) token = 0;
        const unsigned short* xp = Xbf + ((size_t)view * N_TOK + token) * D_MODEL;
        #pragma unroll
        for (int ks = 0; ks < 8; ks++)
            areg[ks] = *(const s16x8*)(xp + ks * 32 + quad * 8);
    }
    dma_half(wchunk + 16384, Wbuf + 16384, wave, lane);   // W2[0], lands during GEMM1[0]

    f32x4 acc2[2][4];
    #pragma unroll
    for (int i = 0; i < 2; i++)
        #pragma unroll
        for (int j = 0; j < 4; j++) acc2[i][j] = (f32x4){0.f, 0.f, 0.f, 0.f};

    for (int c = 0; c < NCH; c++) {
        // ---- GEMM1: 16 rows x 32 cols per wave, K=256
        f32x4 acc1[2];
        acc1[0] = (f32x4){0.f, 0.f, 0.f, 0.f};
        acc1[1] = (f32x4){0.f, 0.f, 0.f, 0.f};
        #pragma unroll
        for (int ks = 0; ks < 8; ks++) {
            #pragma unroll
            for (int nt = 0; nt < 2; nt++) {
                s16x8 b = *(const s16x8*)&Wbuf[((ks * 4 + nh * 2 + nt) * 64 + lane) * 8];
                acc1[nt] = __builtin_amdgcn_mfma_f32_16x16x32_bf16(areg[ks], b, acc1[nt], 0, 0, 0);
            }
        }
        // ---- bias + gelu -> Hc (A-frag order for GEMM2)
        #pragma unroll
        for (int nt = 0; nt < 2; nt++) {
            float bb = b1[e * HDIM + c * CH + (nh * 2 + nt) * 16 + lmod];
            int qa = nt * 2 + (lmod >> 3);
            int baseo = ((mt1 * 2 + nh) * 64 + qa * 16 + quad * 4) * 8 + (lmod & 7);
            #pragma unroll
            for (int r = 0; r < 4; r++) {
                float h = acc1[nt][r] + bb;
                float u = h * (0.7978845608f + 0.0356774081f * h * h);
                float ex2 = __expf(2.f * u);
                float tn = 1.f - 2.f * __builtin_amdgcn_rcpf(1.f + ex2);
                Hc[baseo + r * 8] = f2bf(0.5f * h * (1.f + tn));
            }
        }
        __syncthreads();   // drains W2[c] DMA; Hc visible; GEMM1 done with W1 half
        if (c < NCH - 1)   // W1[c+1] (lands during GEMM2)
            dma_half(wchunk + (size_t)(c + 1) * REC_ELTS, Wbuf, wave, lane);
        // ---- GEMM2: 32 rows x 64 cols per wave, K=64
        #pragma unroll
        for (int ks2 = 0; ks2 < 2; ks2++) {
            s16x8 afr[2];
            #pragma unroll
            for (int mt = 0; mt < 2; mt++)
                afr[mt] = *(const s16x8*)&Hc[(((ms * 2 + mt) * 2 + ks2) * 64 + lane) * 8];
            #pragma unroll
            for (int nt = 0; nt < 4; nt++) {
                s16x8 b = *(const s16x8*)&Wbuf[16384 + ((ks2 * 16 + ns * 4 + nt) * 64 + lane) * 8];
                #pragma unroll
                for (int mt = 0; mt < 2; mt++)
                    acc2[mt][nt] = __builtin_amdgcn_mfma_f32_16x16x32_bf16(
                        afr[mt], b, acc2[mt][nt], 0, 0, 0);
            }
        }
        __syncthreads();   // drains W1[c+1] DMA; GEMM2 done with W2 half + Hc
        if (c < NCH - 1)   // W2[c+1] (lands during GEMM1[c+1]+gelu)
            dma_half(wchunk + (size_t)(c + 1) * REC_ELTS + 16384, Wbuf + 16384, wave, lane);
    }

    // epilogue: out[token] += gate * (acc2 + b2)
    #pragma unroll
    for (int nt = 0; nt < 4; nt++) {
        int col = (ns * 4 + nt) * 16 + lmod;
        float b2v = b2[e * D_MODEL + col];
        #pragma unroll
        for (int mt = 0; mt < 2; mt++) {
            #pragma unroll
            for (int r = 0; r < 4; r++) {
                int rloc = (ms * 2 + mt) * 16 + quad * 4 + r;
                if (r0 + rloc < L) {
                    atomicAdd(&out[(size_t)tokS[rloc] * D_MODEL + col],
                              gateS[rloc] * (acc2[mt][nt][r] + b2v));
                }
            }
        }
    }
}

// ------------------------------------------------------------------
extern "C" void kernel_launch(void* const* d_in, const int* in_sizes, int n_in,
                              void* d_out, int out_size, void* d_ws, size_t ws_size,
                              hipStream_t stream)
{
    const float* v0   = (const float*)d_in[0];
    const float* v1   = (const float*)d_in[1];
    const float* v2   = (const float*)d_in[2];
    const float* rw   = (const float*)d_in[3];
    const float* keys = (const float*)d_in[4];
    const float* W1   = (const float*)d_in[5];
    const float* b1   = (const float*)d_in[6];
    const float* W2   = (const float*)d_in[7];
    const float* b2   = (const float*)d_in[8];
    float* out = (float*)d_out;

    char* p = (char*)d_ws;
    unsigned short* Xbf = (unsigned short*)p; p += (size_t)N_VIEWS * N_TOK * D_MODEL * 2;
    unsigned short* Wf  = (unsigned short*)p; p += (size_t)N_EXP * NCH * REC_ELTS * 2;
    int*   counts = (int*)p;   p += 256;
    int*   offs   = (int*)p;   p += 256;
    int*   cursor = (int*)p;   p += 256;
    int*   spill  = (int*)p;   p += 256;
    int*   tiles  = (int*)p;   p += NT_TOTAL * 4 + 64;
    int*   gidx   = (int*)p;   p += (size_t)N_VIEWS * N_TOK * TOPK * 4;
    float* ggate  = (float*)p; p += (size_t)N_VIEWS * N_TOK * TOPK * 4;
    int*   rowTok = (int*)p;   p += (size_t)N_VIEWS * N_TOK * TOPK * 4;
    float* rowGate= (float*)p; p += (size_t)N_VIEWS * N_TOK * TOPK * 4;

    hipMemsetAsync(counts, 0, NGROUP * sizeof(int), stream);
    hipMemsetAsync(out, 0, (size_t)out_size * sizeof(float), stream);

    prep_kernel<<<896, 256, 0, stream>>>(v0, v1, v2, rw, keys, W1, W2,
                                         Wf, Xbf, gidx, ggate, counts);
    scan_kernel<<<1, 64, 0, stream>>>(counts, offs, cursor, tiles, spill);
    fill_kernel<<<dim3(N_TOK / 256, N_VIEWS), 256, 0, stream>>>(gidx, ggate, cursor,
                                                                rowTok, rowGate);
    ffn_kernel<<<dim3(NT_TOTAL), 512, 0, stream>>>(Xbf, Wf, b1, b2, offs, tiles,
                                                   rowTok, rowGate, out);
}